// Round 5
// baseline (1620.435 us; speedup 1.0000x reference)
//
#include <hip/hip_runtime.h>

#define NN 50000
#define EE 800000
#define DD 128
#define RR 8
#define CELLS (NN * RR)            // 400000 (rel, dst) cells, key = rel*NN + dst (REL-MAJOR)
#define TILE_N 64
#define NBLK ((NN + TILE_N - 1) / TILE_N)          // 782
#define SCAN_CHUNK 1024
#define SCAN_BLOCKS ((CELLS + SCAN_CHUNK - 1) / SCAN_CHUNK)   // 391

typedef __attribute__((ext_vector_type(4))) float f32x4;
typedef __attribute__((ext_vector_type(8))) short s16x8;
union ABu { uint4 q; s16x8 v; };

// ---------------- bf16 helpers ----------------

__device__ __forceinline__ unsigned int packbf2(float a, float b) {
    unsigned int ua = __float_as_uint(a);
    unsigned int ub = __float_as_uint(b);
    ua = (ua + 0x7fffu + ((ua >> 16) & 1u)) >> 16;           // RNE, low half
    ub = (ub + 0x7fffu + ((ub >> 16) & 1u)) & 0xffff0000u;   // RNE, high half
    return ua | ub;
}

// ---------------- fused prep: to_bf16 + wpack + rpack + count_cells ----------------
#define NB_A ((NN * 32 + 255) / 256)    // 6250: x -> packed bf16 (float4 -> uint2)
#define NB_B 128                        // wpack: 32768 items
#define NB_C 32                         // rpack: 8192 items
#define NB_D ((EE + 255) / 256)         // 3125: count_cells

__global__ void prep_fused(const float* __restrict__ x, unsigned int* __restrict__ xb,
                           const float* __restrict__ W1, const float* __restrict__ W2,
                           unsigned int* __restrict__ Wb1, unsigned int* __restrict__ Wb2,
                           const float* __restrict__ r1, const float* __restrict__ r2,
                           unsigned int* __restrict__ rb1, unsigned int* __restrict__ rb2,
                           const int* __restrict__ dst, const int* __restrict__ et,
                           int* __restrict__ cnt) {
    int bid = blockIdx.x, tid = threadIdx.x;
    if (bid < NB_A) {
        int i = bid * 256 + tid;
        if (i < NN * 32) {
            float4 v = ((const float4*)x)[i];
            ((uint2*)xb)[i] = make_uint2(packbf2(v.x, v.y), packbf2(v.z, v.w));
        }
    } else if (bid < NB_A + NB_B) {
        // W [16 blocks of 64x64, row-major (k,n)] -> Wb [block][n][kp]
        // mapping: n fastest -> coalesced reads; scattered writes (fire-and-forget)
        int i = (bid - NB_A) * 256 + tid;
        int n = i & 63, kp = (i >> 6) & 31, rb = i >> 11;
        int s0 = (rb * 64 + 2 * kp) * 64 + n;
        int s1 = (rb * 64 + 2 * kp + 1) * 64 + n;
        Wb1[((rb * 64 + n) * 32) + kp] = packbf2(W1[s0], W1[s1]);
        Wb2[((rb * 64 + n) * 32) + kp] = packbf2(W2[s0], W2[s1]);
    } else if (bid < NB_A + NB_B + NB_C) {
        // root [128k x 128n] -> rb [n][kp]; n fastest -> coalesced reads
        int i = (bid - NB_A - NB_B) * 256 + tid;
        int n = i & 127, kp = i >> 7;
        int s0 = (2 * kp) * 128 + n, s1 = (2 * kp + 1) * 128 + n;
        rb1[n * 64 + kp] = packbf2(r1[s0], r1[s1]);
        rb2[n * 64 + kp] = packbf2(r2[s0], r2[s1]);
    } else {
        int e = (bid - NB_A - NB_B - NB_C) * 256 + tid;
        if (e < EE) atomicAdd(&cnt[et[e] * NN + dst[e]], 1);
    }
}

// ---------------- prep: scans + scatter (CSR by cell = rel*NN + dst) ----------------

__global__ __launch_bounds__(256) void scan1(const int* __restrict__ cnt,
                                             int* __restrict__ off, int* __restrict__ bsum) {
    __shared__ int s[256];
    int tid = threadIdx.x;
    int base = blockIdx.x * SCAN_CHUNK + tid * 4;
    int v[4];
#pragma unroll
    for (int i = 0; i < 4; ++i) v[i] = (base + i < CELLS) ? cnt[base + i] : 0;
    int tot = v[0] + v[1] + v[2] + v[3];
    s[tid] = tot;
    __syncthreads();
    for (int d = 1; d < 256; d <<= 1) {
        int t = (tid >= d) ? s[tid - d] : 0;
        __syncthreads();
        s[tid] += t;
        __syncthreads();
    }
    int excl = s[tid] - tot;
    if (tid == 255) bsum[blockIdx.x] = s[255];
    int run = excl;
#pragma unroll
    for (int i = 0; i < 4; ++i) {
        if (base + i < CELLS) off[base + i] = run;
        run += v[i];
    }
}

// merged scan2+scan3: each block reduces its own chunk-prefix from bsum, then finalizes
__global__ __launch_bounds__(256) void scan3(int* __restrict__ off, const int* __restrict__ bsum,
                                             int* __restrict__ cur) {
    __shared__ int red[256];
    int tid = threadIdx.x, bid = blockIdx.x;
    int a = 0;
    for (int i = tid; i < bid; i += 256) a += bsum[i];
    red[tid] = a;
    __syncthreads();
#pragma unroll
    for (int d = 128; d > 0; d >>= 1) {
        if (tid < d) red[tid] += red[tid + d];
        __syncthreads();
    }
    int add = red[0];
    int base = bid * SCAN_CHUNK + tid * 4;
#pragma unroll
    for (int i = 0; i < 4; ++i) {
        int c = base + i;
        if (c < CELLS) {
            int o = off[c] + add;
            off[c] = o;
            cur[c] = o;
        }
    }
    if (bid == 0 && tid == 0) off[CELLS] = EE;   // sentinel
}

// scatter: per-edge record (src<<6 | dst&63, 1/cnt) sorted by cell.
// dst&63 is the node's local row in its tile because TILE_N == 64 and tiles are aligned.
__global__ void cell_scatter(const int* __restrict__ src, const int* __restrict__ dst,
                             const int* __restrict__ et, int* __restrict__ cur,
                             const int* __restrict__ cnt, uint2* __restrict__ epack) {
    int e = blockIdx.x * blockDim.x + threadIdx.x;
    if (e < EE) {
        int d = dst[e];
        int cell = et[e] * NN + d;
        int pos = atomicAdd(&cur[cell], 1);
        float sc = 1.0f / (float)cnt[cell];
        epack[pos] = make_uint2(((unsigned int)src[e] << 6) | (unsigned int)(d & 63),
                                __float_as_uint(sc));
    }
}

// ---------------- fused layer, MFMA GEMM ----------------
// Gather v5: 8-lane-GROUP-per-edge, edge-balanced, LDS fp32 atomic accumulation.
//   Wave = 8 groups x 8 lanes; per step each group handles one edge: the 8 lanes read
//   the 256B bf16 row contiguously (2 cache lines/group -> 16 lines/instr, 4x less TA
//   pressure than node-per-lane), pre-scale by 1/cnt (epack), ds_add_f32 into
//   ACC[node][feat].  Edges split across waves strided-8 by EDGE COUNT -> no
//   max-degree-lane serialization (R3/R4's gate).  ~20 VGPR of gather state -> no
//   spills (R4's gate).  8 edges/wave-step -> 8x R2's edge parallelism (R2's gate).
// Per relation: gather(atomics->ACC) | bar | convert ACC->MT bf16 + re-zero | bar |
//   mfma(r).  gather(r+1) overlaps stragglers' mfma(r) (ACC vs MT disjoint).
// LDS: MT[64kp][67] 17.2KB + ACC[64][130] 33.3KB (also epilogue OF) = 50.4KB
//   -> 3 blocks/CU (151.3KB of 160KB), 24 waves/CU.
template <int RELU, int WRITEF, int WRITEB>
__global__ __launch_bounds__(512, 6) void layer_fused(
    const unsigned int* __restrict__ xgb, const uint2* __restrict__ epck,
    const int* __restrict__ off,
    const unsigned int* __restrict__ Wb, const unsigned int* __restrict__ rootb,
    const float* __restrict__ bias, float* __restrict__ outf,
    unsigned int* __restrict__ outb) {

    __shared__ unsigned int MT[64 * 67];     // packed bf16 A-tile [kpair][node]
    __shared__ float ACC[64 * 130];          // fp32 accum [node][feat]; also epilogue OF

    int tid = threadIdx.x;
    int n0 = blockIdx.x * TILE_N;
    int w = tid >> 6, l = tid & 63;          // wave (0..7), lane
    int quad = l >> 4, li = l & 15;
    int b = w >> 2;                          // block (out-half) this wave serves
    int nloc = (w & 3) * 16 + li;            // out-col within block
    int g = l >> 3, sub = l & 7;             // gather: group, sub-lane (32B of row)

    f32x4 acc[4];
    {
        float bb = bias[16 * w + li];
#pragma unroll
        for (int mt = 0; mt < 4; ++mt) {
            acc[mt][0] = bb; acc[mt][1] = bb; acc[mt][2] = bb; acc[mt][3] = bb;
        }
    }

    // per-relation CSR ranges: lanes 0..7 hold begins, 8..15 ends; shfl-broadcast later
    int rng = 0;
    {
        int nend = n0 + TILE_N; if (nend > NN) nend = NN;
        if (l < 8)       rng = off[l * NN + n0];
        else if (l < 16) rng = off[(l - 8) * NN + nend];
    }

    // zero ACC: thread covers node l, feature pairs {w, w+8, ..., w+56}
#pragma unroll
    for (int k = 0; k < 8; ++k)
        *(float2*)&ACC[l * 130 + 2 * (w + 8 * k)] = make_float2(0.f, 0.f);
    __syncthreads();

#define MFMA_BLOCK(rr) do {                                                           \
    const uint4* WbB = (const uint4*)(Wb + (((size_t)(rr) * 2 + b) * 64) * 32);       \
    _Pragma("unroll") for (int kc = 0; kc < 2; ++kc) {                                \
        ABu bf; bf.q = WbB[nloc * 8 + 4 * kc + quad];                                 \
        _Pragma("unroll") for (int mt = 0; mt < 4; ++mt) {                            \
            ABu af; int base_ = (32 * b + 16 * kc + 4 * quad) * 67 + 16 * mt + li;    \
            af.q.x = MT[base_];       af.q.y = MT[base_ + 67];                        \
            af.q.z = MT[base_ + 134]; af.q.w = MT[base_ + 201];                       \
            acc[mt] = __builtin_amdgcn_mfma_f32_16x16x32_bf16(af.v, bf.v, acc[mt], 0, 0, 0); \
        } } } while (0)

    for (int r = 0; r < RR; ++r) {
        // ---- edge-balanced gather: group g of wave w takes edges obeg+w*8+g+64k ----
        int obeg = __shfl(rng, r);
        int oend = __shfl(rng, 8 + r);

        int t = obeg + w * 8 + g;
        bool has = t < oend;
        uint2 ep; uint4 A, B;
        if (has) {
            ep = epck[t];                                          // 8 lanes broadcast
            const uint4* p = (const uint4*)(xgb + (ep.x & 0xffffffc0u) + sub * 8);
            A = p[0]; B = p[1];                                    // contiguous 32B
        }
        while (__any(has)) {
            int t2 = t + 64;
            bool has2 = t2 < oend;
            uint2 ep2; uint4 A2, B2;
            if (has2) {
                ep2 = epck[t2];
                const uint4* p = (const uint4*)(xgb + (ep2.x & 0xffffffc0u) + sub * 8);
                A2 = p[0]; B2 = p[1];
            }
            if (has) {
                int nl = (int)(ep.x & 63u);
                float sc = __uint_as_float(ep.y);
                float* dA = &ACC[nl * 130 + sub * 16];
                unsigned int u[8] = {A.x, A.y, A.z, A.w, B.x, B.y, B.z, B.w};
#pragma unroll
                for (int i = 0; i < 8; ++i) {
                    atomicAdd(&dA[2 * i],     __uint_as_float(u[i] << 16) * sc);
                    atomicAdd(&dA[2 * i + 1], __uint_as_float(u[i] & 0xffff0000u) * sc);
                }
            }
            t = t2; has = has2; ep = ep2; A = A2; B = B2;
        }
        __syncthreads();

        // ---- convert ACC -> MT (packed bf16, [kpair][node] stride 67), re-zero ----
#pragma unroll
        for (int k = 0; k < 8; ++k) {
            int kp = w + 8 * k;                                    // wave-uniform
            float2 v = *(float2*)&ACC[l * 130 + 2 * kp];
            MT[kp * 67 + l] = packbf2(v.x, v.y);
            *(float2*)&ACC[l * 130 + 2 * kp] = make_float2(0.f, 0.f);
        }
        __syncthreads();

        // ---- block-diag GEMM: 8 mfma/wave; A from MT, B from global Wb (L1-hot) ----
        MFMA_BLOCK(r);
        // no barrier: gather(r+1) writes only ACC (disjoint from MT); convert(r+1)
        // is behind the next bar1, which every wave reaches only after mfma(r).
    }
    __syncthreads();     // all waves done mfma(7) before MT overwrite

    // ---- root term: MT <- own row (already packed bf16: direct copy) ----
    {
        int node = n0 + l;
        if (node < NN) {
            const uint4* xr = (const uint4*)(xgb + (size_t)node * 64 + w * 8);
            uint4 X0 = xr[0], X1 = xr[1];
            MT[(8 * w + 0) * 67 + l] = X0.x;
            MT[(8 * w + 1) * 67 + l] = X0.y;
            MT[(8 * w + 2) * 67 + l] = X0.z;
            MT[(8 * w + 3) * 67 + l] = X0.w;
            MT[(8 * w + 4) * 67 + l] = X1.x;
            MT[(8 * w + 5) * 67 + l] = X1.y;
            MT[(8 * w + 6) * 67 + l] = X1.z;
            MT[(8 * w + 7) * 67 + l] = X1.w;
        } else {
#pragma unroll
            for (int i = 0; i < 8; ++i) MT[(8 * w + i) * 67 + l] = 0u;
        }
    }
    __syncthreads();

    // root GEMM: K=128 -> 4 k-chunks, 16 mfma/wave
    const uint4* RbB = (const uint4*)rootb;
#pragma unroll
    for (int kc = 0; kc < 4; ++kc) {
        ABu bf;
        bf.q = RbB[(16 * w + li) * 16 + 4 * kc + quad];
#pragma unroll
        for (int mt = 0; mt < 4; ++mt) {
            ABu af;
            int base = (16 * kc + 4 * quad) * 67 + 16 * mt + li;
            af.q.x = MT[base]; af.q.y = MT[base + 67];
            af.q.z = MT[base + 134]; af.q.w = MT[base + 201];
            acc[mt] = __builtin_amdgcn_mfma_f32_16x16x32_bf16(af.v, bf.v, acc[mt], 0, 0, 0);
        }
    }
    __syncthreads();

    // ---- epilogue: stage D to LDS (fp32, stride 130, in ACC region), coalesced stores ----
    float* OF = ACC;
#pragma unroll
    for (int mt = 0; mt < 4; ++mt)
#pragma unroll
        for (int reg = 0; reg < 4; ++reg)
            OF[(16 * mt + 4 * quad + reg) * 130 + 16 * w + li] = acc[mt][reg];
    __syncthreads();

    if (WRITEB) {
        int p = tid & 63, rg = tid >> 6;     // pair-col, row-group (8 rows/pass)
#pragma unroll 4
        for (int it = 0; it < 8; ++it) {
            int ee = it * 8 + rg, row = n0 + ee;
            if (row < NN) {
                float v0 = OF[ee * 130 + 2 * p], v1 = OF[ee * 130 + 2 * p + 1];
                if (RELU) { v0 = fmaxf(v0, 0.f); v1 = fmaxf(v1, 0.f); }
                outb[(size_t)row * 64 + p] = packbf2(v0, v1);
            }
        }
    }
    if (WRITEF) {
        int d4 = (tid & 31) * 4, rg = tid >> 5;   // 16 rows/pass
#pragma unroll 4
        for (int it = 0; it < 4; ++it) {
            int ee = it * 16 + rg, row = n0 + ee;
            if (row < NN) {
                float4 v = make_float4(OF[ee * 130 + d4], OF[ee * 130 + d4 + 1],
                                       OF[ee * 130 + d4 + 2], OF[ee * 130 + d4 + 3]);
                if (RELU) {
                    v.x = fmaxf(v.x, 0.f); v.y = fmaxf(v.y, 0.f);
                    v.z = fmaxf(v.z, 0.f); v.w = fmaxf(v.w, 0.f);
                }
                *(float4*)(outf + (size_t)row * DD + d4) = v;
            }
        }
    }
#undef MFMA_BLOCK
}

// ---------------- driver ----------------

extern "C" void kernel_launch(void* const* d_in, const int* in_sizes, int n_in,
                              void* d_out, int out_size, void* d_ws, size_t ws_size,
                              hipStream_t stream) {
    const float* x     = (const float*)d_in[0];
    const int*   ei    = (const int*)d_in[1];
    const int*   src   = ei;
    const int*   dstp  = ei + EE;
    const int*   et    = (const int*)d_in[2];
    const float* W1    = (const float*)d_in[3];
    const float* root1 = (const float*)d_in[4];
    const float* b1    = (const float*)d_in[5];
    const float* W2    = (const float*)d_in[6];
    const float* root2 = (const float*)d_in[7];
    const float* b2    = (const float*)d_in[8];
    float* out = (float*)d_out;

    // ws layout (4 B elements)
    unsigned int* xb  = (unsigned int*)d_ws;         // NN*64 packed bf16 pairs
    unsigned int* hb  = xb + (size_t)NN * 64;        // NN*64
    int* cnt  = (int*)(hb + (size_t)NN * 64);        // CELLS
    int* off  = cnt + CELLS;                         // CELLS + 1
    int* cur  = off + CELLS + 1;                     // CELLS
    int* bsum = cur + CELLS;                         // 512 (+1 pad for 8B alignment)
    uint2* epack = (uint2*)(bsum + 513);             // EE uint2 (8B-aligned)
    unsigned int* Wb1 = (unsigned int*)(epack + EE); // 32768
    unsigned int* Wb2 = Wb1 + 32768;                 // 32768
    unsigned int* rb1 = Wb2 + 32768;                 // 8192
    unsigned int* rb2 = rb1 + 8192;                  // 8192

    hipMemsetAsync(cnt, 0, CELLS * sizeof(int), stream);
    prep_fused<<<NB_A + NB_B + NB_C + NB_D, 256, 0, stream>>>(
        x, xb, W1, W2, Wb1, Wb2, root1, root2, rb1, rb2, dstp, et, cnt);
    scan1<<<SCAN_BLOCKS, 256, 0, stream>>>(cnt, off, bsum);
    scan3<<<SCAN_BLOCKS, 256, 0, stream>>>(off, bsum, cur);
    cell_scatter<<<(EE + 255) / 256, 256, 0, stream>>>(src, dstp, et, cur, cnt, epack);

    // layer 1: bf16 h out;  layer 2: fp32 out
    layer_fused<1, 0, 1><<<NBLK, 512, 0, stream>>>(xb, epack, off, Wb1, rb1, b1,
                                                   nullptr, hb);
    layer_fused<0, 1, 0><<<NBLK, 512, 0, stream>>>(hb, epack, off, Wb2, rb2, b2,
                                                   out, nullptr);
}

// Round 6
// 480.602 us; speedup vs baseline: 3.3717x; 3.3717x over previous
//
#include <hip/hip_runtime.h>

#define NN 50000
#define EE 800000
#define DD 128
#define RR 8
#define CELLS (NN * RR)            // 400000 (rel, dst) cells, key = rel*NN + dst (REL-MAJOR)
#define TILE_N 64
#define NBLK ((NN + TILE_N - 1) / TILE_N)          // 782
#define SCAN_CHUNK 1024
#define SCAN_BLOCKS ((CELLS + SCAN_CHUNK - 1) / SCAN_CHUNK)   // 391

typedef __attribute__((ext_vector_type(4))) float f32x4;
typedef __attribute__((ext_vector_type(8))) short s16x8;
union ABu { uint4 q; s16x8 v; };

// ---------------- bf16 helpers ----------------

__device__ __forceinline__ unsigned int packbf2(float a, float b) {
    unsigned int ua = __float_as_uint(a);
    unsigned int ub = __float_as_uint(b);
    ua = (ua + 0x7fffu + ((ua >> 16) & 1u)) >> 16;           // RNE, low half
    ub = (ub + 0x7fffu + ((ub >> 16) & 1u)) & 0xffff0000u;   // RNE, high half
    return ua | ub;
}

// ---------------- fused prep: to_bf16 + wpack + rpack + count_cells ----------------
#define NB_A ((NN * 32 + 255) / 256)    // 6250: x -> packed bf16 (float4 -> uint2)
#define NB_B 128                        // wpack: 32768 items
#define NB_C 32                         // rpack: 8192 items
#define NB_D ((EE + 255) / 256)         // 3125: count_cells

__global__ void prep_fused(const float* __restrict__ x, unsigned int* __restrict__ xb,
                           const float* __restrict__ W1, const float* __restrict__ W2,
                           unsigned int* __restrict__ Wb1, unsigned int* __restrict__ Wb2,
                           const float* __restrict__ r1, const float* __restrict__ r2,
                           unsigned int* __restrict__ rb1, unsigned int* __restrict__ rb2,
                           const int* __restrict__ dst, const int* __restrict__ et,
                           int* __restrict__ cnt) {
    int bid = blockIdx.x, tid = threadIdx.x;
    if (bid < NB_A) {
        int i = bid * 256 + tid;
        if (i < NN * 32) {
            float4 v = ((const float4*)x)[i];
            ((uint2*)xb)[i] = make_uint2(packbf2(v.x, v.y), packbf2(v.z, v.w));
        }
    } else if (bid < NB_A + NB_B) {
        // W [16 blocks of 64x64, row-major (k,n)] -> Wb [block][n][kp]
        // mapping: n fastest -> coalesced reads; scattered writes (fire-and-forget)
        int i = (bid - NB_A) * 256 + tid;
        int n = i & 63, kp = (i >> 6) & 31, rb = i >> 11;
        int s0 = (rb * 64 + 2 * kp) * 64 + n;
        int s1 = (rb * 64 + 2 * kp + 1) * 64 + n;
        Wb1[((rb * 64 + n) * 32) + kp] = packbf2(W1[s0], W1[s1]);
        Wb2[((rb * 64 + n) * 32) + kp] = packbf2(W2[s0], W2[s1]);
    } else if (bid < NB_A + NB_B + NB_C) {
        // root [128k x 128n] -> rb [n][kp]; n fastest -> coalesced reads
        int i = (bid - NB_A - NB_B) * 256 + tid;
        int n = i & 127, kp = i >> 7;
        int s0 = (2 * kp) * 128 + n, s1 = (2 * kp + 1) * 128 + n;
        rb1[n * 64 + kp] = packbf2(r1[s0], r1[s1]);
        rb2[n * 64 + kp] = packbf2(r2[s0], r2[s1]);
    } else {
        int e = (bid - NB_A - NB_B - NB_C) * 256 + tid;
        if (e < EE) atomicAdd(&cnt[et[e] * NN + dst[e]], 1);
    }
}

// ---------------- prep: scans + scatter (CSR by cell = rel*NN + dst) ----------------

__global__ __launch_bounds__(256) void scan1(const int* __restrict__ cnt,
                                             int* __restrict__ off, int* __restrict__ bsum) {
    __shared__ int s[256];
    int tid = threadIdx.x;
    int base = blockIdx.x * SCAN_CHUNK + tid * 4;
    int v[4];
#pragma unroll
    for (int i = 0; i < 4; ++i) v[i] = (base + i < CELLS) ? cnt[base + i] : 0;
    int tot = v[0] + v[1] + v[2] + v[3];
    s[tid] = tot;
    __syncthreads();
    for (int d = 1; d < 256; d <<= 1) {
        int t = (tid >= d) ? s[tid - d] : 0;
        __syncthreads();
        s[tid] += t;
        __syncthreads();
    }
    int excl = s[tid] - tot;
    if (tid == 255) bsum[blockIdx.x] = s[255];
    int run = excl;
#pragma unroll
    for (int i = 0; i < 4; ++i) {
        if (base + i < CELLS) off[base + i] = run;
        run += v[i];
    }
}

// merged scan2+scan3: each block reduces its own chunk-prefix from bsum, then finalizes
__global__ __launch_bounds__(256) void scan3(int* __restrict__ off, const int* __restrict__ bsum,
                                             int* __restrict__ cur) {
    __shared__ int red[256];
    int tid = threadIdx.x, bid = blockIdx.x;
    int a = 0;
    for (int i = tid; i < bid; i += 256) a += bsum[i];
    red[tid] = a;
    __syncthreads();
#pragma unroll
    for (int d = 128; d > 0; d >>= 1) {
        if (tid < d) red[tid] += red[tid + d];
        __syncthreads();
    }
    int add = red[0];
    int base = bid * SCAN_CHUNK + tid * 4;
#pragma unroll
    for (int i = 0; i < 4; ++i) {
        int c = base + i;
        if (c < CELLS) {
            int o = off[c] + add;
            off[c] = o;
            cur[c] = o;
        }
    }
    if (bid == 0 && tid == 0) off[CELLS] = EE;   // sentinel
}

// scatter: per-edge record (src<<6 | dst&63), sorted by cell.
// dst&63 is the node's local row in its tile because TILE_N == 64 and tiles are aligned.
__global__ void cell_scatter(const int* __restrict__ src, const int* __restrict__ dst,
                             const int* __restrict__ et, int* __restrict__ cur,
                             int* __restrict__ esrc) {
    int e = blockIdx.x * blockDim.x + threadIdx.x;
    if (e < EE) {
        int d = dst[e];
        int cell = et[e] * NN + d;
        int pos = atomicAdd(&cur[cell], 1);
        esrc[pos] = (int)(((unsigned int)src[e] << 6) | (unsigned int)(d & 63));
    }
}

// ---------------- fused layer: indicator-GEMM aggregation + MFMA transform ----------------
// Per (tile=64 nodes, relation): edges in chunks of 64.
//   stage G[feat 128][edge-pair 33] bf16-pairs: wave w loads rows e=8w..8w+7, each a
//     single coalesced 256B global_load_dword (lane = feat-pair), independent -> 8-deep
//     latency overlap, zero imbalance, zero chains.
//   build S[edge-pair 32][node 66] 0/1 bf16: wave w owns rows 4w..4w+3 (zero + scatter
//     of its own 8 edge records) -> wave-local LDS ordering, no extra barrier.
//   agg MFMA: accS[node][feat] += S^T x G (8 mfma/wave/chunk, fp32 accumulate in regs).
// After chunks: scale by 1/cnt (fp32, exact, LDS table CF), pack feat-pairs via
//   __shfl_xor(1), write MT[kp][node]; transform GEMM = verified R3 code.
// S/G disjoint from MT -> gather(r+1) overlaps transform(r) across waves.
// No atomics, no serial walks, <=8 row-uints in flight (no spills).
// LDS: G 16.9K + S 8.4K + MT 17.2K + CF 2K = 44.5KB (epilogue OF unions over all) -> 3 blk/CU.
template <int RELU, int WRITEF, int WRITEB>
__global__ __launch_bounds__(512, 4) void layer_fused(
    const unsigned int* __restrict__ xgb, const unsigned int* __restrict__ epk,
    const int* __restrict__ off,
    const unsigned int* __restrict__ Wb, const unsigned int* __restrict__ rootb,
    const float* __restrict__ bias, float* __restrict__ outf,
    unsigned int* __restrict__ outb) {

    __shared__ __align__(16) unsigned int SH[11136];   // 44544 B
    unsigned int* GB  = SH;               // [128 feat][33 ep] uints (bf16 k-pairs)
    unsigned int* SS  = SH + 4224;        // [32 ep][66 node] uints (bf16 k-pairs)
    unsigned int* MTp = SH + 6336;        // [64 kp][67 node]
    float*        CF  = (float*)(SH + 10624);   // [8 rel][64 node] 1/cnt

    int tid = threadIdx.x;
    int n0 = blockIdx.x * TILE_N;
    int w = tid >> 6, l = tid & 63;
    int quad = l >> 4, li = l & 15;
    int b = w >> 2;                       // out-half this wave serves (transform)
    int nloc = (w & 3) * 16 + li;         // out-col within block (transform)
    int node = n0 + l;

    f32x4 acc[4];
    {
        float bb = bias[16 * w + li];
#pragma unroll
        for (int mt = 0; mt < 4; ++mt) {
            acc[mt][0] = bb; acc[mt][1] = bb; acc[mt][2] = bb; acc[mt][3] = bb;
        }
    }

    // per-relation tile edge ranges: lanes 0..7 hold begins, 8..15 ends
    int rng = 0;
    {
        int nend = n0 + TILE_N; if (nend > NN) nend = NN;
        if (l < 8)       rng = off[l * NN + n0];
        else if (l < 16) rng = off[(l - 8) * NN + nend];
    }

    // zero G once (stale-chunk columns are masked by S=0; must be finite)
    uint4 z4 = make_uint4(0u, 0u, 0u, 0u);
    ((uint4*)GB)[tid] = z4;
    ((uint4*)GB)[512 + tid] = z4;
    if (tid < 32) ((uint4*)GB)[1024 + tid] = z4;

    // 1/cnt table (exact fp32 divide at convert time)
    if (w == 0) {
        for (int r = 0; r < RR; ++r) {
            float sc = 1.0f;
            if (node < NN) {
                int c = r * NN + node;
                int ct = off[c + 1] - off[c];
                sc = 1.0f / (float)max(ct, 1);
            }
            CF[r * 64 + l] = sc;
        }
    }
    __syncthreads();

    for (int r = 0; r < RR; ++r) {
        int obeg = __shfl(rng, r);
        int oend = __shfl(rng, 8 + r);
        int nch = (oend - obeg + 63) >> 6;
        if (nch == 0) continue;           // tile-uniform; skipping transform is exact

        f32x4 accS[4];
#pragma unroll
        for (int mt = 0; mt < 4; ++mt) {
            accS[mt][0] = 0.f; accS[mt][1] = 0.f; accS[mt][2] = 0.f; accS[mt][3] = 0.f;
        }

        for (int ch = 0; ch < nch; ++ch) {
            int t0 = obeg + ch * 64;
            int m = oend - t0; if (m > 64) m = 64;
            if (ch > 0) __syncthreads();         // protect S/G from prev-chunk readers

            // zero own S rows (4w..4w+3), 264 uints, wave-local
            int sbase = (4 * w) * 66;
#pragma unroll
            for (int k = 0; k < 4; ++k) SS[sbase + k * 64 + l] = 0u;
            if (l < 8) SS[sbase + 256 + l] = 0u;

            // build S: lane j<8 of wave w owns edge e=8w+j (row 4w+j/2 -> own rows)
            unsigned int rec = 0u;
            if (l < 8 && 8 * w + l < m) {
                rec = epk[t0 + 8 * w + l];
                ((unsigned short*)SS)[((4 * w + (l >> 1)) * 66 + (rec & 63u)) * 2 + (l & 1)] = 0x3F80u;
            }

            // stage G rows e=8w..8w+7: coalesced 256B/row, repack as k-pairs (transposed)
            unsigned int uu[8];
#pragma unroll
            for (int j = 0; j < 8; ++j) {
                unsigned int rj = __shfl(rec, j);
                uu[j] = (8 * w + j < m) ? xgb[(rj & 0xffffffc0u) + (unsigned)l] : 0u;
            }
            unsigned short* GUS = (unsigned short*)GB;
#pragma unroll
            for (int j = 0; j < 8; ++j) {
                int e = 8 * w + j;
                if (e < m) {
                    GUS[((2 * l) * 33 + (e >> 1)) * 2 + (e & 1)]     = (unsigned short)(uu[j] & 0xffffu);
                    GUS[((2 * l + 1) * 33 + (e >> 1)) * 2 + (e & 1)] = (unsigned short)(uu[j] >> 16);
                }
            }
            __syncthreads();

            // agg GEMM: accS[node][feat] += S^T x G  (m=node, k=64 edges, n=feat 16w..16w+15)
#pragma unroll
            for (int kc = 0; kc < 2; ++kc) {
                ABu bf;
                int gb = (16 * w + li) * 33 + 16 * kc + 4 * quad;
                bf.q.x = GB[gb]; bf.q.y = GB[gb + 1]; bf.q.z = GB[gb + 2]; bf.q.w = GB[gb + 3];
#pragma unroll
                for (int mt = 0; mt < 4; ++mt) {
                    ABu af;
                    int sb = (16 * kc + 4 * quad) * 66 + 16 * mt + li;
                    af.q.x = SS[sb]; af.q.y = SS[sb + 66]; af.q.z = SS[sb + 132]; af.q.w = SS[sb + 198];
                    accS[mt] = __builtin_amdgcn_mfma_f32_16x16x32_bf16(af.v, bf.v, accS[mt], 0, 0, 0);
                }
            }
        }

        // convert accS -> MT: scale 1/cnt (fp32), pack feat-pairs via lane-xor shuffle
#pragma unroll
        for (int mt = 0; mt < 4; ++mt) {
#pragma unroll
            for (int j = 0; j < 4; ++j) {
                int nd = 16 * mt + 4 * quad + j;                 // node
                float v = accS[mt][j] * CF[r * 64 + nd];
                float vp = __shfl_xor(v, 1);                     // partner feat
                if (!(li & 1))
                    MTp[(8 * w + (li >> 1)) * 67 + nd] = packbf2(v, vp);
            }
        }
        __syncthreads();                                         // MT complete

        // transform GEMM (verified): 8 mfma/wave, B from pre-packed Wb (L1-hot)
        const uint4* WbB = (const uint4*)(Wb + (((size_t)r * 2 + b) * 64) * 32);
#pragma unroll
        for (int kc = 0; kc < 2; ++kc) {
            ABu bf;
            bf.q = WbB[nloc * 8 + 4 * kc + quad];
#pragma unroll
            for (int mt = 0; mt < 4; ++mt) {
                ABu af;
                int base_ = (32 * b + 16 * kc + 4 * quad) * 67 + 16 * mt + li;
                af.q.x = MTp[base_]; af.q.y = MTp[base_ + 67];
                af.q.z = MTp[base_ + 134]; af.q.w = MTp[base_ + 201];
                acc[mt] = __builtin_amdgcn_mfma_f32_16x16x32_bf16(af.v, bf.v, acc[mt], 0, 0, 0);
            }
        }
        // no trailing barrier: next relation's S/G writes are disjoint from MT/Wb,
        // and its pre-mfma barrier orders everything else.
    }
    __syncthreads();     // all waves past transform(last) before MT overwrite

    // ---- root term: MT <- own row (already packed bf16: direct copy) ----
    if (node < NN) {
        const uint4* xr = (const uint4*)(xgb + (size_t)node * 64 + w * 8);
        uint4 X0 = xr[0], X1 = xr[1];
        MTp[(8 * w + 0) * 67 + l] = X0.x;
        MTp[(8 * w + 1) * 67 + l] = X0.y;
        MTp[(8 * w + 2) * 67 + l] = X0.z;
        MTp[(8 * w + 3) * 67 + l] = X0.w;
        MTp[(8 * w + 4) * 67 + l] = X1.x;
        MTp[(8 * w + 5) * 67 + l] = X1.y;
        MTp[(8 * w + 6) * 67 + l] = X1.z;
        MTp[(8 * w + 7) * 67 + l] = X1.w;
    } else {
#pragma unroll
        for (int i = 0; i < 8; ++i) MTp[(8 * w + i) * 67 + l] = 0u;
    }
    __syncthreads();

    // root GEMM: K=128 -> 4 k-chunks, 16 mfma/wave
    const uint4* RbB = (const uint4*)rootb;
#pragma unroll
    for (int kc = 0; kc < 4; ++kc) {
        ABu bf;
        bf.q = RbB[(16 * w + li) * 16 + 4 * kc + quad];
#pragma unroll
        for (int mt = 0; mt < 4; ++mt) {
            ABu af;
            int base = (16 * kc + 4 * quad) * 67 + 16 * mt + li;
            af.q.x = MTp[base]; af.q.y = MTp[base + 67];
            af.q.z = MTp[base + 134]; af.q.w = MTp[base + 201];
            acc[mt] = __builtin_amdgcn_mfma_f32_16x16x32_bf16(af.v, bf.v, acc[mt], 0, 0, 0);
        }
    }
    __syncthreads();

    // ---- epilogue: stage D to LDS (fp32, stride 130), then coalesced stores ----
    float* OF = (float*)SH;
#pragma unroll
    for (int mt = 0; mt < 4; ++mt)
#pragma unroll
        for (int reg = 0; reg < 4; ++reg)
            OF[(16 * mt + 4 * quad + reg) * 130 + 16 * w + li] = acc[mt][reg];
    __syncthreads();

    if (WRITEB) {
        int p = tid & 63, rg = tid >> 6;     // pair-col, row-group (8 rows/pass)
#pragma unroll 4
        for (int it = 0; it < 8; ++it) {
            int ee = it * 8 + rg, row = n0 + ee;
            if (row < NN) {
                float v0 = OF[ee * 130 + 2 * p], v1 = OF[ee * 130 + 2 * p + 1];
                if (RELU) { v0 = fmaxf(v0, 0.f); v1 = fmaxf(v1, 0.f); }
                outb[(size_t)row * 64 + p] = packbf2(v0, v1);
            }
        }
    }
    if (WRITEF) {
        int d4 = (tid & 31) * 4, rg = tid >> 5;   // 16 rows/pass
#pragma unroll 4
        for (int it = 0; it < 4; ++it) {
            int ee = it * 16 + rg, row = n0 + ee;
            if (row < NN) {
                float4 v = make_float4(OF[ee * 130 + d4], OF[ee * 130 + d4 + 1],
                                       OF[ee * 130 + d4 + 2], OF[ee * 130 + d4 + 3]);
                if (RELU) {
                    v.x = fmaxf(v.x, 0.f); v.y = fmaxf(v.y, 0.f);
                    v.z = fmaxf(v.z, 0.f); v.w = fmaxf(v.w, 0.f);
                }
                *(float4*)(outf + (size_t)row * DD + d4) = v;
            }
        }
    }
}

// ---------------- driver ----------------

extern "C" void kernel_launch(void* const* d_in, const int* in_sizes, int n_in,
                              void* d_out, int out_size, void* d_ws, size_t ws_size,
                              hipStream_t stream) {
    const float* x     = (const float*)d_in[0];
    const int*   ei    = (const int*)d_in[1];
    const int*   src   = ei;
    const int*   dstp  = ei + EE;
    const int*   et    = (const int*)d_in[2];
    const float* W1    = (const float*)d_in[3];
    const float* root1 = (const float*)d_in[4];
    const float* b1    = (const float*)d_in[5];
    const float* W2    = (const float*)d_in[6];
    const float* root2 = (const float*)d_in[7];
    const float* b2    = (const float*)d_in[8];
    float* out = (float*)d_out;

    // ws layout (4 B elements)
    unsigned int* xb  = (unsigned int*)d_ws;         // NN*64 packed bf16 pairs
    unsigned int* hb  = xb + (size_t)NN * 64;        // NN*64
    int* cnt  = (int*)(hb + (size_t)NN * 64);        // CELLS
    int* off  = cnt + CELLS;                         // CELLS + 1
    int* cur  = off + CELLS + 1;                     // CELLS
    int* bsum = cur + CELLS;                         // 512
    int* esrc = bsum + 512;                          // EE (packed src<<6|nl records)
    unsigned int* Wb1 = (unsigned int*)(esrc + EE);  // 32768
    unsigned int* Wb2 = Wb1 + 32768;                 // 32768
    unsigned int* rb1 = Wb2 + 32768;                 // 8192
    unsigned int* rb2 = rb1 + 8192;                  // 8192

    hipMemsetAsync(cnt, 0, CELLS * sizeof(int), stream);
    prep_fused<<<NB_A + NB_B + NB_C + NB_D, 256, 0, stream>>>(
        x, xb, W1, W2, Wb1, Wb2, root1, root2, rb1, rb2, dstp, et, cnt);
    scan1<<<SCAN_BLOCKS, 256, 0, stream>>>(cnt, off, bsum);
    scan3<<<SCAN_BLOCKS, 256, 0, stream>>>(off, bsum, cur);
    cell_scatter<<<(EE + 255) / 256, 256, 0, stream>>>(src, dstp, et, cur, esrc);

    // layer 1: bf16 h out;  layer 2: fp32 out
    layer_fused<1, 0, 1><<<NBLK, 512, 0, stream>>>(xb, (const unsigned int*)esrc, off,
                                                   Wb1, rb1, b1, nullptr, hb);
    layer_fused<0, 1, 0><<<NBLK, 512, 0, stream>>>(hb, (const unsigned int*)esrc, off,
                                                   Wb2, rb2, b2, out, nullptr);
}

// Round 7
// 377.747 us; speedup vs baseline: 4.2897x; 1.2723x over previous
//
#include <hip/hip_runtime.h>

#define NN 50000
#define EE 800000
#define DD 128
#define RR 8
#define CELLS (NN * RR)            // 400000 (rel, dst) cells, key = rel*NN + dst (REL-MAJOR)
#define TILE_N 64
#define NBLK ((NN + TILE_N - 1) / TILE_N)          // 782
#define SCAN_CHUNK 1024
#define SCAN_BLOCKS ((CELLS + SCAN_CHUNK - 1) / SCAN_CHUNK)   // 391

typedef __attribute__((ext_vector_type(4))) float f32x4;
typedef __attribute__((ext_vector_type(8))) short s16x8;
union ABu { uint4 q; s16x8 v; };

// ---------------- bf16 helpers ----------------

__device__ __forceinline__ unsigned int packbf2(float a, float b) {
    unsigned int ua = __float_as_uint(a);
    unsigned int ub = __float_as_uint(b);
    ua = (ua + 0x7fffu + ((ua >> 16) & 1u)) >> 16;           // RNE, low half
    ub = (ub + 0x7fffu + ((ub >> 16) & 1u)) & 0xffff0000u;   // RNE, high half
    return ua | ub;
}

// unpack 2 uint4 (16 bf16) and add into sA[0..15]
__device__ __forceinline__ void upadd16(float* sA, uint4 a, uint4 b) {
    unsigned int u[8] = {a.x, a.y, a.z, a.w, b.x, b.y, b.z, b.w};
#pragma unroll
    for (int j = 0; j < 8; ++j) {
        sA[2 * j]     += __uint_as_float(u[j] << 16);
        sA[2 * j + 1] += __uint_as_float(u[j] & 0xffff0000u);
    }
}

// ---------------- fused prep: to_bf16 + wpack + rpack + count_cells ----------------
#define NB_A ((NN * 32 + 255) / 256)    // 6250: x -> packed bf16 (float4 -> uint2)
#define NB_B 128                        // wpack: 32768 items
#define NB_C 32                         // rpack: 8192 items
#define NB_D ((EE + 255) / 256)         // 3125: count_cells

__global__ void prep_fused(const float* __restrict__ x, unsigned int* __restrict__ xb,
                           const float* __restrict__ W1, const float* __restrict__ W2,
                           unsigned int* __restrict__ Wb1, unsigned int* __restrict__ Wb2,
                           const float* __restrict__ r1, const float* __restrict__ r2,
                           unsigned int* __restrict__ rb1, unsigned int* __restrict__ rb2,
                           const int* __restrict__ dst, const int* __restrict__ et,
                           int* __restrict__ cnt) {
    int bid = blockIdx.x, tid = threadIdx.x;
    if (bid < NB_A) {
        int i = bid * 256 + tid;
        if (i < NN * 32) {
            float4 v = ((const float4*)x)[i];
            ((uint2*)xb)[i] = make_uint2(packbf2(v.x, v.y), packbf2(v.z, v.w));
        }
    } else if (bid < NB_A + NB_B) {
        // W [16 blocks of 64x64, row-major (k,n)] -> Wb [block][n][kp]
        // mapping: n fastest -> coalesced reads; scattered writes (fire-and-forget)
        int i = (bid - NB_A) * 256 + tid;
        int n = i & 63, kp = (i >> 6) & 31, rb = i >> 11;
        int s0 = (rb * 64 + 2 * kp) * 64 + n;
        int s1 = (rb * 64 + 2 * kp + 1) * 64 + n;
        Wb1[((rb * 64 + n) * 32) + kp] = packbf2(W1[s0], W1[s1]);
        Wb2[((rb * 64 + n) * 32) + kp] = packbf2(W2[s0], W2[s1]);
    } else if (bid < NB_A + NB_B + NB_C) {
        // root [128k x 128n] -> rb [n][kp]; n fastest -> coalesced reads
        int i = (bid - NB_A - NB_B) * 256 + tid;
        int n = i & 127, kp = i >> 7;
        int s0 = (2 * kp) * 128 + n, s1 = (2 * kp + 1) * 128 + n;
        rb1[n * 64 + kp] = packbf2(r1[s0], r1[s1]);
        rb2[n * 64 + kp] = packbf2(r2[s0], r2[s1]);
    } else {
        int e = (bid - NB_A - NB_B - NB_C) * 256 + tid;
        if (e < EE) atomicAdd(&cnt[et[e] * NN + dst[e]], 1);
    }
}

// ---------------- prep: scans + scatter (CSR by cell = rel*NN + dst) ----------------

__global__ __launch_bounds__(256) void scan1(const int* __restrict__ cnt,
                                             int* __restrict__ off, int* __restrict__ bsum) {
    __shared__ int s[256];
    int tid = threadIdx.x;
    int base = blockIdx.x * SCAN_CHUNK + tid * 4;
    int v[4];
#pragma unroll
    for (int i = 0; i < 4; ++i) v[i] = (base + i < CELLS) ? cnt[base + i] : 0;
    int tot = v[0] + v[1] + v[2] + v[3];
    s[tid] = tot;
    __syncthreads();
    for (int d = 1; d < 256; d <<= 1) {
        int t = (tid >= d) ? s[tid - d] : 0;
        __syncthreads();
        s[tid] += t;
        __syncthreads();
    }
    int excl = s[tid] - tot;
    if (tid == 255) bsum[blockIdx.x] = s[255];
    int run = excl;
#pragma unroll
    for (int i = 0; i < 4; ++i) {
        if (base + i < CELLS) off[base + i] = run;
        run += v[i];
    }
}

// merged scan2+scan3: each block reduces its own chunk-prefix from bsum, then finalizes
__global__ __launch_bounds__(256) void scan3(int* __restrict__ off, const int* __restrict__ bsum,
                                             int* __restrict__ cur) {
    __shared__ int red[256];
    int tid = threadIdx.x, bid = blockIdx.x;
    int a = 0;
    for (int i = tid; i < bid; i += 256) a += bsum[i];
    red[tid] = a;
    __syncthreads();
#pragma unroll
    for (int d = 128; d > 0; d >>= 1) {
        if (tid < d) red[tid] += red[tid + d];
        __syncthreads();
    }
    int add = red[0];
    int base = bid * SCAN_CHUNK + tid * 4;
#pragma unroll
    for (int i = 0; i < 4; ++i) {
        int c = base + i;
        if (c < CELLS) {
            int o = off[c] + add;
            off[c] = o;
            cur[c] = o;
        }
    }
    if (bid == 0 && tid == 0) off[CELLS] = EE;   // sentinel
}

__global__ void cell_scatter(const int* __restrict__ src, const int* __restrict__ dst,
                             const int* __restrict__ et, int* __restrict__ cur,
                             int* __restrict__ esrc) {
    int e = blockIdx.x * blockDim.x + threadIdx.x;
    if (e < EE) {
        int cell = et[e] * NN + dst[e];
        int pos = atomicAdd(&cur[cell], 1);
        esrc[pos] = src[e];
    }
}

// ---------------- fused layer, MFMA GEMM ----------------
// R3 structure (node-per-lane, 512t, sA[16]/thread, no spills) with the latency
// chains removed:
//   - ov/nv preloaded for all 8 relations (16 coalesced loads, issued once)
//   - 6-slot esrc prefetch per relation, issued BEFORE the barrier+mfma(r-1)
//     -> index latency fully hidden (covers P(ne<=6)=99.5%; serial overflow for rest)
//   - row loads in a 3-deep static ring (A/B[3], 24 VGPR, dies before MFMA)
//     -> exposed row latency ~2 waits/relation instead of ~ne serial chains
//   - double-buffered MT -> ONE barrier per relation
// Live state across MFMA: ov/nv 16 + s 6 + acc 16 (~40) -> no spill at (512,4).
// LDS: 2 x MT[64kp][67] = 34.3KB (unions epilogue OF 33.3KB) -> 4 blocks/CU.
#define MTSZ 4288   // 64*67 dwords per MT buffer
#define NPRE 6

template <int RELU, int WRITEF, int WRITEB>
__global__ __launch_bounds__(512, 4) void layer_fused(
    const unsigned int* __restrict__ xgb, const int* __restrict__ esrc,
    const int* __restrict__ off,
    const unsigned int* __restrict__ Wb, const unsigned int* __restrict__ rootb,
    const float* __restrict__ bias, float* __restrict__ outf,
    unsigned int* __restrict__ outb) {

    __shared__ unsigned int SH[2 * MTSZ];    // 34304 B union (OF needs 33280 B)

    int tid = threadIdx.x;
    int n0 = blockIdx.x * TILE_N;
    int e = tid & 63, q = tid >> 6;          // gather: lane-node, k-eighth (16 feats)
    int w = q, l = e;                        // gemm: wave (0..7), lane
    int quad = l >> 4, li = l & 15;
    int b = w >> 2;                          // block (out-half) this wave serves
    int nloc = (w & 3) * 16 + li;            // out-col within block

    f32x4 acc[4];
    {
        float bb = bias[16 * w + li];
#pragma unroll
        for (int mt = 0; mt < 4; ++mt) {
            acc[mt][0] = bb; acc[mt][1] = bb; acc[mt][2] = bb; acc[mt][3] = bb;
        }
    }

    int node = n0 + e;

    // preload per-relation CSR ranges (coalesced; 16 independent loads)
    int ov[RR], nv[RR];
#pragma unroll
    for (int r = 0; r < RR; ++r) {
        if (node < NN) {
            int c = r * NN + node;
            int o = off[c];
            ov[r] = o;
            nv[r] = off[c + 1] - o;
        } else { ov[r] = 0; nv[r] = 0; }
    }

    // esrc prefetch for r=0 (6 independent loads)
    int s[NPRE];
    {
        int o = ov[0], ne = nv[0];
#pragma unroll
        for (int j = 0; j < NPRE; ++j) s[j] = (j < ne) ? esrc[o + j] : 0;
    }

#define MFMA_BLOCK(MTbase, rr) do {                                                   \
    const uint4* WbB = (const uint4*)(Wb + (((size_t)(rr) * 2 + b) * 64) * 32);       \
    _Pragma("unroll") for (int kc = 0; kc < 2; ++kc) {                                \
        ABu bf; bf.q = WbB[nloc * 8 + 4 * kc + quad];                                 \
        _Pragma("unroll") for (int mt = 0; mt < 4; ++mt) {                            \
            ABu af; int base_ = (32 * b + 16 * kc + 4 * quad) * 67 + 16 * mt + li;    \
            af.q.x = (MTbase)[base_];       af.q.y = (MTbase)[base_ + 67];            \
            af.q.z = (MTbase)[base_ + 134]; af.q.w = (MTbase)[base_ + 201];           \
            acc[mt] = __builtin_amdgcn_mfma_f32_16x16x32_bf16(af.v, bf.v, acc[mt], 0, 0, 0); \
        } } } while (0)

#pragma unroll
    for (int r = 0; r < RR; ++r) {
        int o = ov[r], ne = nv[r];

        // ---- gather: 3-deep ring over prefetched indices ----
        float sA[16];
#pragma unroll
        for (int i = 0; i < 16; ++i) sA[i] = 0.f;

        uint4 A[3], B[3];
#pragma unroll
        for (int j = 0; j < 3; ++j)
            if (j < ne) {
                const uint4* p = (const uint4*)(xgb + (size_t)s[j] * 64 + q * 8);
                A[j] = p[0]; B[j] = p[1];
            }
#pragma unroll
        for (int j = 0; j < NPRE; ++j) {
            if (j < ne) {
                upadd16(sA, A[j % 3], B[j % 3]);
                if (j + 3 < NPRE && j + 3 < ne) {
                    const uint4* p = (const uint4*)(xgb + (size_t)s[j + 3] * 64 + q * 8);
                    A[j % 3] = p[0]; B[j % 3] = p[1];
                }
            }
        }
        if (ne > NPRE) {                       // rare (P ~ 0.5% of lanes)
            for (int t = NPRE; t < ne; ++t) {
                int u = esrc[o + t];
                const uint4* p = (const uint4*)(xgb + (size_t)u * 64 + q * 8);
                uint4 X = p[0], Y = p[1];
                upadd16(sA, X, Y);
            }
        }
        float sc = 1.0f / (float)max(ne, 1);

        // ---- esrc prefetch for r+1: latency hides under MT write + bar + mfma(r) ----
        if (r + 1 < RR) {
            int o2 = ov[r + 1], ne2 = nv[r + 1];
#pragma unroll
            for (int j = 0; j < NPRE; ++j) s[j] = (j < ne2) ? esrc[o2 + j] : 0;
        }

        // ---- MT write (dbuf r&1), one barrier, mfma(r) ----
        unsigned int* MTW = SH + (r & 1) * MTSZ;
#pragma unroll
        for (int i = 0; i < 8; ++i)
            MTW[(8 * q + i) * 67 + e] = packbf2(sA[2 * i] * sc, sA[2 * i + 1] * sc);
        __syncthreads();
        MFMA_BLOCK(SH + (r & 1) * MTSZ, r);
        // no second barrier: next iteration writes the OTHER MT buffer; the next
        // barrier (pre-mfma) orders buffer reuse two iterations apart.
    }

    // ---- root term: MT0 <- own row (disjoint from MT1 read by any wave in r=7 mfma) ----
    if (node < NN) {
        const uint4* xr = (const uint4*)(xgb + (size_t)node * 64 + q * 8);
        uint4 X0 = xr[0], X1 = xr[1];
        SH[(8 * q + 0) * 67 + e] = X0.x;
        SH[(8 * q + 1) * 67 + e] = X0.y;
        SH[(8 * q + 2) * 67 + e] = X0.z;
        SH[(8 * q + 3) * 67 + e] = X0.w;
        SH[(8 * q + 4) * 67 + e] = X1.x;
        SH[(8 * q + 5) * 67 + e] = X1.y;
        SH[(8 * q + 6) * 67 + e] = X1.z;
        SH[(8 * q + 7) * 67 + e] = X1.w;
    } else {
#pragma unroll
        for (int i = 0; i < 8; ++i) SH[(8 * q + i) * 67 + e] = 0u;
    }
    __syncthreads();

    // root GEMM: K=128 -> 4 k-chunks, 16 mfma/wave
    const uint4* RbB = (const uint4*)rootb;
#pragma unroll
    for (int kc = 0; kc < 4; ++kc) {
        ABu bf;
        bf.q = RbB[(16 * w + li) * 16 + 4 * kc + quad];
#pragma unroll
        for (int mt = 0; mt < 4; ++mt) {
            ABu af;
            int base = (16 * kc + 4 * quad) * 67 + 16 * mt + li;
            af.q.x = SH[base]; af.q.y = SH[base + 67];
            af.q.z = SH[base + 134]; af.q.w = SH[base + 201];
            acc[mt] = __builtin_amdgcn_mfma_f32_16x16x32_bf16(af.v, bf.v, acc[mt], 0, 0, 0);
        }
    }
    __syncthreads();

    // ---- epilogue: stage D to LDS (fp32, stride 130), then coalesced stores ----
    float* OF = (float*)SH;
#pragma unroll
    for (int mt = 0; mt < 4; ++mt)
#pragma unroll
        for (int reg = 0; reg < 4; ++reg)
            OF[(16 * mt + 4 * quad + reg) * 130 + 16 * w + li] = acc[mt][reg];
    __syncthreads();

    if (WRITEB) {
        int p = tid & 63, rg = tid >> 6;     // pair-col, row-group (8 rows/pass)
#pragma unroll 4
        for (int it = 0; it < 8; ++it) {
            int ee = it * 8 + rg, row = n0 + ee;
            if (row < NN) {
                float v0 = OF[ee * 130 + 2 * p], v1 = OF[ee * 130 + 2 * p + 1];
                if (RELU) { v0 = fmaxf(v0, 0.f); v1 = fmaxf(v1, 0.f); }
                outb[(size_t)row * 64 + p] = packbf2(v0, v1);
            }
        }
    }
    if (WRITEF) {
        int d4 = (tid & 31) * 4, rg = tid >> 5;   // 16 rows/pass
#pragma unroll 4
        for (int it = 0; it < 4; ++it) {
            int ee = it * 16 + rg, row = n0 + ee;
            if (row < NN) {
                float4 v = make_float4(OF[ee * 130 + d4], OF[ee * 130 + d4 + 1],
                                       OF[ee * 130 + d4 + 2], OF[ee * 130 + d4 + 3]);
                if (RELU) {
                    v.x = fmaxf(v.x, 0.f); v.y = fmaxf(v.y, 0.f);
                    v.z = fmaxf(v.z, 0.f); v.w = fmaxf(v.w, 0.f);
                }
                *(float4*)(outf + (size_t)row * DD + d4) = v;
            }
        }
    }
#undef MFMA_BLOCK
}

// ---------------- driver ----------------

extern "C" void kernel_launch(void* const* d_in, const int* in_sizes, int n_in,
                              void* d_out, int out_size, void* d_ws, size_t ws_size,
                              hipStream_t stream) {
    const float* x     = (const float*)d_in[0];
    const int*   ei    = (const int*)d_in[1];
    const int*   src   = ei;
    const int*   dstp  = ei + EE;
    const int*   et    = (const int*)d_in[2];
    const float* W1    = (const float*)d_in[3];
    const float* root1 = (const float*)d_in[4];
    const float* b1    = (const float*)d_in[5];
    const float* W2    = (const float*)d_in[6];
    const float* root2 = (const float*)d_in[7];
    const float* b2    = (const float*)d_in[8];
    float* out = (float*)d_out;

    // ws layout (4 B elements)
    unsigned int* xb  = (unsigned int*)d_ws;         // NN*64 packed bf16 pairs
    unsigned int* hb  = xb + (size_t)NN * 64;        // NN*64
    int* cnt  = (int*)(hb + (size_t)NN * 64);        // CELLS
    int* off  = cnt + CELLS;                         // CELLS + 1
    int* cur  = off + CELLS + 1;                     // CELLS
    int* bsum = cur + CELLS;                         // 512
    int* esrc = bsum + 512;                          // EE
    unsigned int* Wb1 = (unsigned int*)(esrc + EE);  // 32768
    unsigned int* Wb2 = Wb1 + 32768;                 // 32768
    unsigned int* rb1 = Wb2 + 32768;                 // 8192
    unsigned int* rb2 = rb1 + 8192;                  // 8192

    hipMemsetAsync(cnt, 0, CELLS * sizeof(int), stream);
    prep_fused<<<NB_A + NB_B + NB_C + NB_D, 256, 0, stream>>>(
        x, xb, W1, W2, Wb1, Wb2, root1, root2, rb1, rb2, dstp, et, cnt);
    scan1<<<SCAN_BLOCKS, 256, 0, stream>>>(cnt, off, bsum);
    scan3<<<SCAN_BLOCKS, 256, 0, stream>>>(off, bsum, cur);
    cell_scatter<<<(EE + 255) / 256, 256, 0, stream>>>(src, dstp, et, cur, esrc);

    // layer 1: bf16 h out;  layer 2: fp32 out
    layer_fused<1, 0, 1><<<NBLK, 512, 0, stream>>>(xb, esrc, off, Wb1, rb1, b1,
                                                   nullptr, hb);
    layer_fused<0, 1, 0><<<NBLK, 512, 0, stream>>>(hb, esrc, off, Wb2, rb2, b2,
                                                   out, nullptr);
}